// Round 5
// baseline (241.643 us; speedup 1.0000x reference)
//
#include <hip/hip_runtime.h>

#define BN 16
#define LL 2048
#define DD 256
#define XS 516   // padded row stride for X (floats); 516%4==0 -> float4-aligned rows

typedef __attribute__((ext_vector_type(8))) short bf16x8;
typedef __attribute__((ext_vector_type(4))) float f32x4;

__device__ __forceinline__ unsigned int f2bf1(float f) {
    union { float f; unsigned int i; } v; v.f = f;
    return (v.i + 0x7fffu + ((v.i >> 16) & 1u)) >> 16;
}
__device__ __forceinline__ float bfval(unsigned int h) {
    union { unsigned int i; float f; } v; v.i = h << 16;
    return v.f;
}
__device__ __forceinline__ unsigned int pk2bf(float a, float b) {   // RNE pack
    return f2bf1(a) | (f2bf1(b) << 16);
}

// ROUND-11 GREEN KERNEL, restored byte-for-byte. Stage 1: hidden =
// (k*gate*mask) @ emb via bf16 MFMA, scores hi/lo-compensated, emb RNE-hi.
// Stage 2: generator GEMM via bf16 MFMA, in-register operand conversion.
__global__ __launch_bounds__(256, 2)
void tpp_v11(const float* __restrict__ et,
             const float* __restrict__ noise,
             const float* __restrict__ gp,
             const float* __restrict__ lsc,
             const float* __restrict__ Wn,
             const float* __restrict__ Wi,
             const float* __restrict__ wt,
             const float* __restrict__ bt,
             const float* __restrict__ gam,
             const float* __restrict__ bet,
             float* __restrict__ out) {
    __shared__ __align__(16) unsigned short sA[4 * 64 * 8];   // score hi A-frags
    __shared__ __align__(16) unsigned short sAl[4 * 64 * 8];  // score lo A-frags
    __shared__ float tIs[32];
    __shared__ float tJs[64];
    __shared__ __align__(16) float X[32][XS];  // cols 0..255 noise, 256..511 hidden/h

    const int tid = threadIdx.x;
    const int w   = tid >> 6;    // wave 0..3
    const int ln  = tid & 63;    // lane
    const int qd  = ln >> 4;     // quad 0..3
    const int n16 = ln & 15;

    const int bidx  = blockIdx.x;
    const int b     = bidx & (BN - 1);
    const int itile = 63 - (bidx >> 4);       // heaviest blocks first
    const int i0    = itile * 32;

    // ---- scalars ----
    const float lgt = 1.0f / (1.0f + __expf(-gp[0]));
    const float sgt = 1.0f / (1.0f + __expf(-gp[1]));
    const float ls  = log1pf(__expf(lsc[0]));
    const float inv_ls2 = 1.0f / (ls * ls);
    const float inv_T   = 1.0f / 200.0f;
    const float inv_s2  = 2.0f / sgt;

    // stage-1 emb per-lane constants: d = w*64 + cg*16 + n16
    float ipv4[4];
#pragma unroll
    for (int cg = 0; cg < 4; ++cg)
        ipv4[cg] = __expf(-(float)(w * 64 + cg * 16 + n16) * 0.0719557841532429f);
    const float offl = (n16 & 1) ? 1.57079632679489662f : 0.0f;  // cos = sin(x+pi/2)

    // ---- noise -> X[.][0..255] (fp32, coalesced), tIs ----
    {
        const float* nptr = noise + ((size_t)b * LL + i0) * DD;
        for (int idx = tid; idx < 32 * 64; idx += 256) {
            int row = idx >> 6, c4 = idx & 63;
            *(float4*)&X[row][c4 * 4] = *(const float4*)(nptr + (size_t)row * DD + c4 * 4);
        }
    }
    if (tid < 32) tIs[tid] = et[(size_t)b * LL + i0 + tid];

    // score-thread mapping: t -> (m, g, quad, ks)
    const int sm  = tid & 15;
    const int sg  = (tid >> 4) & 1;
    const int sqd = (tid >> 5) & 3;
    const int sks = tid >> 7;

    f32x4 acc[2][4];
#pragma unroll
    for (int g = 0; g < 2; ++g)
#pragma unroll
        for (int cg = 0; cg < 4; ++cg) {
            f32x4 z = {0.f, 0.f, 0.f, 0.f};
            acc[g][cg] = z;
        }

    // ---- stage 1: causal j-tiles of 64, bf16 MFMA, scores hi/lo compensated ----
    const int ntile = (i0 >> 6) + 1;
    for (int jt = 0; jt < ntile; ++jt) {
        const int j0 = jt * 64;
        __syncthreads();   // protects sA/sAl/tJs reuse; covers noise/tIs staging at jt=0
        if (tid < 64) tJs[tid] = et[(size_t)b * LL + j0 + tid];

        {
            const float* etb = et + (size_t)b * LL + j0 + sks * 32 + sqd * 8;
            float ti = tIs[sg * 16 + sm];
            int gi = i0 + sg * 16 + sm;
            int jb = j0 + sks * 32 + sqd * 8;
            unsigned int hb[8];
            float lo[8];
#pragma unroll
            for (int jj = 0; jj < 8; ++jj) {
                float tj = etb[jj];
                float dt = fabsf(ti - tj);
                float kk = __expf(-dt * dt * inv_ls2);
                float x2 = (dt * inv_T - lgt) * inv_s2;
                float gate = __fdividef(2.0f, 1.0f + __expf(-x2));
                float s = kk * gate;
                if (gi < jb + jj) s = 0.0f;
                hb[jj] = f2bf1(s);
                lo[jj] = s - bfval(hb[jj]);
            }
            int base = ((sks * 2 + sg) * 64 + sqd * 16 + sm) * 8;
            uint4 rh, rl;
            rh.x = hb[0] | (hb[1] << 16); rh.y = hb[2] | (hb[3] << 16);
            rh.z = hb[4] | (hb[5] << 16); rh.w = hb[6] | (hb[7] << 16);
            rl.x = pk2bf(lo[0], lo[1]); rl.y = pk2bf(lo[2], lo[3]);
            rl.z = pk2bf(lo[4], lo[5]); rl.w = pk2bf(lo[6], lo[7]);
            *(uint4*)&sA[base]  = rh;
            *(uint4*)&sAl[base] = rl;
        }
        __syncthreads();

        // MFMA phase: scores hi+lo from LDS, emb RNE-hi built in registers
#pragma unroll
        for (int ks = 0; ks < 2; ++ks) {
            bf16x8 a0h = *(const bf16x8*)&sA[((ks * 2 + 0) * 64 + ln) * 8];
            bf16x8 a1h = *(const bf16x8*)&sA[((ks * 2 + 1) * 64 + ln) * 8];
            bf16x8 a0l = *(const bf16x8*)&sAl[((ks * 2 + 0) * 64 + ln) * 8];
            bf16x8 a1l = *(const bf16x8*)&sAl[((ks * 2 + 1) * 64 + ln) * 8];
            float tj[8];
#pragma unroll
            for (int jj = 0; jj < 8; ++jj) tj[jj] = tJs[ks * 32 + qd * 8 + jj];
#pragma unroll
            for (int cg = 0; cg < 4; ++cg) {
                unsigned int eh[8];
#pragma unroll
                for (int jj = 0; jj < 8; ++jj) {
                    float e = __sinf(fmaf(tj[jj], ipv4[cg], offl));
                    eh[jj] = f2bf1(e);
                }
                union { uint4 u; bf16x8 v; } bh;
                bh.u.x = eh[0] | (eh[1] << 16); bh.u.y = eh[2] | (eh[3] << 16);
                bh.u.z = eh[4] | (eh[5] << 16); bh.u.w = eh[6] | (eh[7] << 16);
                acc[0][cg] = __builtin_amdgcn_mfma_f32_16x16x32_bf16(a0h, bh.v, acc[0][cg], 0, 0, 0);
                acc[0][cg] = __builtin_amdgcn_mfma_f32_16x16x32_bf16(a0l, bh.v, acc[0][cg], 0, 0, 0);
                acc[1][cg] = __builtin_amdgcn_mfma_f32_16x16x32_bf16(a1h, bh.v, acc[1][cg], 0, 0, 0);
                acc[1][cg] = __builtin_amdgcn_mfma_f32_16x16x32_bf16(a1l, bh.v, acc[1][cg], 0, 0, 0);
            }
        }
    }

    // ---- dump C-frags -> X[row][256+col] (row = g*16+qd*4+reg, col = w*64+cg*16+n16) ----
    __syncthreads();
#pragma unroll
    for (int g = 0; g < 2; ++g)
#pragma unroll
        for (int cg = 0; cg < 4; ++cg)
#pragma unroll
            for (int reg = 0; reg < 4; ++reg)
                X[g * 16 + qd * 4 + reg][256 + w * 64 + cg * 16 + n16] = acc[g][cg][reg];
    __syncthreads();

    // ---- LayerNorm in place on X[.][256..511] (wave w owns rows w*8..w*8+7) ----
    {
        float4 gv = *(const float4*)(gam + ln * 4);
        float4 bv = *(const float4*)(bet + ln * 4);
#pragma unroll
        for (int r = 0; r < 8; ++r) {
            int row = w * 8 + r;
            float4 xv = *(const float4*)&X[row][256 + ln * 4];
            float s1 = xv.x + xv.y + xv.z + xv.w;
            float s2 = xv.x * xv.x + xv.y * xv.y + xv.z * xv.z + xv.w * xv.w;
#pragma unroll
            for (int off = 1; off < 64; off <<= 1) {
                s1 += __shfl_xor(s1, off, 64);
                s2 += __shfl_xor(s2, off, 64);
            }
            float mu   = s1 * (1.0f / 256.0f);
            float var  = s2 * (1.0f / 256.0f) - mu * mu;
            float rstd = rsqrtf(var + 1e-6f);
            float4 yv;
            yv.x = (xv.x - mu) * rstd * gv.x + bv.x;
            yv.y = (xv.y - mu) * rstd * gv.y + bv.y;
            yv.z = (xv.z - mu) * rstd * gv.z + bv.z;
            yv.w = (xv.w - mu) * rstd * gv.w + bv.w;
            *(float4*)&X[row][256 + ln * 4] = yv;
        }
    }
    __syncthreads();

    // ---- stage 2: h = relu([noise|hidden] @ [Wn|Wi]^T) via bf16 MFMA ----
    f32x4 acc2[2][4];
#pragma unroll
    for (int g = 0; g < 2; ++g)
#pragma unroll
        for (int cg = 0; cg < 4; ++cg) {
            f32x4 z = {0.f, 0.f, 0.f, 0.f};
            acc2[g][cg] = z;
        }
    for (int ks2 = 0; ks2 < 16; ++ks2) {
        const int kk = ks2 * 32 + qd * 8;
        bf16x8 a[2];
#pragma unroll
        for (int g = 0; g < 2; ++g) {
            const float* xp = &X[g * 16 + n16][kk];
            float4 xa = *(const float4*)xp;
            float4 xc = *(const float4*)(xp + 4);
            union { uint4 u; bf16x8 v; } aa;
            aa.u.x = pk2bf(xa.x, xa.y); aa.u.y = pk2bf(xa.z, xa.w);
            aa.u.z = pk2bf(xc.x, xc.y); aa.u.w = pk2bf(xc.z, xc.w);
            a[g] = aa.v;
        }
        const float* Wbase = (ks2 < 8) ? Wn : Wi;
        const int kw = (ks2 < 8) ? kk : (kk - 256);
#pragma unroll
        for (int cg = 0; cg < 4; ++cg) {
            const int o = (w * 4 + cg) * 16 + n16;
            const float* wp = Wbase + (size_t)o * DD + kw;
            float4 wa = *(const float4*)wp;
            float4 wc = *(const float4*)(wp + 4);
            union { uint4 u; bf16x8 v; } bb;
            bb.u.x = pk2bf(wa.x, wa.y); bb.u.y = pk2bf(wa.z, wa.w);
            bb.u.z = pk2bf(wc.x, wc.y); bb.u.w = pk2bf(wc.z, wc.w);
            acc2[0][cg] = __builtin_amdgcn_mfma_f32_16x16x32_bf16(a[0], bb.v, acc2[0][cg], 0, 0, 0);
            acc2[1][cg] = __builtin_amdgcn_mfma_f32_16x16x32_bf16(a[1], bb.v, acc2[1][cg], 0, 0, 0);
        }
    }

    // ---- dump h C-frags -> X[row][256+col] (same proven pattern) ----
    __syncthreads();
#pragma unroll
    for (int g = 0; g < 2; ++g)
#pragma unroll
        for (int cg = 0; cg < 4; ++cg)
#pragma unroll
            for (int reg = 0; reg < 4; ++reg)
                X[g * 16 + qd * 4 + reg][256 + w * 64 + cg * 16 + n16] = acc2[g][cg][reg];
    __syncthreads();

    // ---- epilogue: softplus(relu(h) . w_time + b_time) ----
    {
        const int d0 = ln * 4;
        float4 wv = *(const float4*)(wt + d0);
        const float btv = bt[0];
#pragma unroll
        for (int r = 0; r < 8; ++r) {
            int row = w * 8 + r;
            float4 hv = *(const float4*)&X[row][256 + d0];
            float p = fmaxf(hv.x, 0.0f) * wv.x + fmaxf(hv.y, 0.0f) * wv.y
                    + fmaxf(hv.z, 0.0f) * wv.z + fmaxf(hv.w, 0.0f) * wv.w;
#pragma unroll
            for (int off = 1; off < 64; off <<= 1) p += __shfl_xor(p, off, 64);
            if (ln == 0) {
                float z  = p + btv;
                float sp = (z > 20.0f) ? z : log1pf(__expf(z));
                out[(size_t)b * LL + i0 + row] = sp;
            }
        }
    }
}

extern "C" void kernel_launch(void* const* d_in, const int* in_sizes, int n_in,
                              void* d_out, int out_size, void* d_ws, size_t ws_size,
                              hipStream_t stream) {
    (void)in_sizes; (void)n_in; (void)out_size; (void)d_ws; (void)ws_size;
    const float* et    = (const float*)d_in[1];
    const float* noise = (const float*)d_in[2];
    const float* gp    = (const float*)d_in[3];
    const float* lsc   = (const float*)d_in[4];
    const float* Wn    = (const float*)d_in[5];
    const float* Wi    = (const float*)d_in[6];
    const float* wt    = (const float*)d_in[7];
    const float* bt    = (const float*)d_in[8];
    const float* gam   = (const float*)d_in[9];
    const float* bet   = (const float*)d_in[10];
    float* out = (float*)d_out;

    tpp_v11<<<dim3(BN * 64), dim3(256), 0, stream>>>(et, noise, gp, lsc, Wn, Wi,
                                                     wt, bt, gam, bet, out);
}